// Round 5
// baseline (2277.007 us; speedup 1.0000x reference)
//
#include <hip/hip_runtime.h>

// Bidirectional LSTM, B=64 S=256 I=H=512, f32 in/out.
// Persistent dataflow kernel: 256 WGs = 8 groups (2 dir x 4 batch-group) x 32 col-slices.
// Weights (fp16, MFMA-frag-packed) LDS-resident.
// Cross-WG h exchange: TAGGED WORDS via relaxed agent-scope (IF$) atomics — word =
// (step_tag << 16) | h_fp16. Consumers poll the h data itself; tag match == data valid.
// Single IF$ round-trip per step; no flags, no store-ack on the critical path.
// Mod-2 h buffering is race-free: publishing step-t data requires having read step-(t-1)
// data, which itself requires every slice's step-(t-1) publication to follow its own
// step-(t-2) reads (data-dependency backpressure; see round-5 analysis).

typedef float    f32x4 __attribute__((ext_vector_type(4)));
typedef _Float16 half8 __attribute__((ext_vector_type(8)));
typedef unsigned long long u64;

#define NB 64
#define NS 256
#define NI 512
#define NH 512

__device__ inline f32x4 zero4() { f32x4 v; v[0]=0.f; v[1]=0.f; v[2]=0.f; v[3]=0.f; return v; }

// ---------------- prep kernels ----------------

__global__ void conv_x(const float* __restrict__ x, _Float16* __restrict__ xb) {
    const int i = blockIdx.x * 256 + threadIdx.x;
    const float4 a = ((const float4*)x)[2*i];
    const float4 b = ((const float4*)x)[2*i+1];
    half8 o;
    o[0]=(_Float16)a.x; o[1]=(_Float16)a.y; o[2]=(_Float16)a.z; o[3]=(_Float16)a.w;
    o[4]=(_Float16)b.x; o[5]=(_Float16)b.y; o[6]=(_Float16)b.z; o[7]=(_Float16)b.w;
    ((half8*)xb)[i] = o;
}

// WP[d][s][p][kk][g][l][j] = W_{d,g}[p*512 + kk*32 + (l>>4)*8 + j][s*16 + (l&15)]
__global__ void pack_w(const float* __restrict__ Wi_f, const float* __restrict__ Wf_f,
                       const float* __restrict__ Wo_f, const float* __restrict__ Wc_f,
                       const float* __restrict__ Wi_b, const float* __restrict__ Wf_b,
                       const float* __restrict__ Wo_b, const float* __restrict__ Wc_b,
                       _Float16* __restrict__ WP) {
    const int idx = blockIdx.x * 256 + threadIdx.x;
    const int l  = idx & 63;
    const int g  = (idx >> 6) & 3;
    const int kk = (idx >> 8) & 15;
    const int p  = (idx >> 12) & 1;
    const int s  = (idx >> 13) & 31;
    const int d  = (idx >> 18) & 1;
    const float* W;
    if (d == 0) W = (g==0) ? Wi_f : (g==1) ? Wf_f : (g==2) ? Wo_f : Wc_f;
    else        W = (g==0) ? Wi_b : (g==1) ? Wf_b : (g==2) ? Wo_b : Wc_b;
    const int r0 = p*512 + kk*32 + (l >> 4)*8;
    const int c  = s*16 + (l & 15);
    half8 v;
    #pragma unroll
    for (int j = 0; j < 8; ++j) v[j] = (_Float16)W[(size_t)(r0 + j)*NH + c];
    *(half8*)(WP + (size_t)idx*8) = v;
}

__global__ void pack_bias(const float* __restrict__ bi_f, const float* __restrict__ bf_f,
                          const float* __restrict__ bo_f, const float* __restrict__ bc_f,
                          const float* __restrict__ bi_b, const float* __restrict__ bf_b,
                          const float* __restrict__ bo_b, const float* __restrict__ bc_b,
                          float* __restrict__ biasP) {
    const int i = blockIdx.x * 256 + threadIdx.x;
    const int c = i & 511, g = (i >> 9) & 3, d = (i >> 11) & 1;
    const float* b;
    if (d == 0) b = (g==0) ? bi_f : (g==1) ? bf_f : (g==2) ? bo_f : bc_f;
    else        b = (g==0) ? bi_b : (g==1) ? bf_b : (g==2) ? bo_b : bc_b;
    biasP[i] = b[c];
}

// ---------------- main persistent scan kernel ----------------
// grid 256 x 256. LDS: 128KiB packed weights + 16KiB reduce buffer -> 1 WG/CU.

__global__ __launch_bounds__(256) void lstm_scan(
    const _Float16* __restrict__ xb,     // [64][256][512]
    const _Float16* __restrict__ WP,     // [2][32][2][16][4][64][8]
    const float*    __restrict__ biasP,  // [2][4][512]
    unsigned*       __restrict__ htag,   // [8 grp][2 buf][16 row][512 col] tagged h words
    float*          __restrict__ out)    // [64][256][1024]
{
    __shared__ char  ldsw[131072];
    __shared__ float redb[4][4][64][4];

    const int wg  = blockIdx.x;
    const int g8  = wg & 7;           // group = (d,bg); &7 keeps group-mates XCD-adjacent (perf only)
    const int s   = wg >> 3;          // column slice (16 h-cols)
    const int d   = g8 >> 2;          // direction
    const int bg  = g8 & 3;           // batch group (16 rows)
    const int tid = threadIdx.x;
    const int w   = tid >> 6;         // wave 0..3 (K-split)
    const int l   = tid & 63;

    // stage packed weight slice (128 KiB) into LDS
    {
        const uint4* src = (const uint4*)(WP + (size_t)(d*32 + s)*65536);
        uint4* dst = (uint4*)ldsw;
        #pragma unroll
        for (int i = 0; i < 32; ++i) dst[tid + i*256] = src[tid + i*256];
    }
    __syncthreads();

    float bias0 = 0.f, bias1 = 0.f, bias2 = 0.f, bias3 = 0.f;
    if (w == 0) {
        const int c = s*16 + (l & 15);
        bias0 = biasP[(d*4 + 0)*512 + c];
        bias1 = biasP[(d*4 + 1)*512 + c];
        bias2 = biasP[(d*4 + 2)*512 + c];
        bias3 = biasP[(d*4 + 3)*512 + c];
    }

    f32x4 acc[4];
    #pragma unroll
    for (int g = 0; g < 4; ++g) acc[g] = zero4();
    f32x4 cst = zero4();                  // cell state (wave 0 only)

    bool dead = false;                    // sticky guard-trip (anti-hang)

    const int arow = bg*16 + (l & 15);    // A-frag row = batch row
    const int kof  = (l >> 4) * 8;        // A/B frag k sub-offset
    const int kk0  = w * 4;               // this wave's first k-chunk

    unsigned* grpbuf = htag + (size_t)g8 * 2 * 16 * 512;

    for (int t = 0; t < NS; ++t) {
        const int u = d ? (NS - 1 - t) : t;   // time index in x/out

        // ---- x A-frag loads + x-part MFMAs (independent of h) ----
        const _Float16* xp = xb + ((size_t)arow*NS + u)*NI + kof;
        half8 af[4];
        #pragma unroll
        for (int c = 0; c < 4; ++c) af[c] = *(const half8*)(xp + (kk0 + c)*32);
        #pragma unroll
        for (int c = 0; c < 4; ++c) {
            #pragma unroll
            for (int g = 0; g < 4; ++g) {
                const half8 b = *(const half8*)(ldsw + ((((kk0 + c)*4 + g) << 10) | (l << 4)));
                acc[g] = __builtin_amdgcn_mfma_f32_16x16x32_f16(af[c], b, acc[g], 0, 0, 0);
            }
        }

        // ---- h-part: poll tagged h words (the data IS the flag), then MFMAs ----
        if (t > 0) {
            const unsigned tagv = (unsigned)t;   // producer wrote tag = t for h_{t-1}
            const unsigned* base = grpbuf + (size_t)(t & 1)*16*512 + (l & 15)*512 + kof;
            u64 q[16];
            {
                int guard = 0; unsigned bad;
                do {
                    bad = 0;
                    #pragma unroll
                    for (int c = 0; c < 4; ++c) {
                        const u64* p = (const u64*)(base + (kk0 + c)*32);
                        #pragma unroll
                        for (int j = 0; j < 4; ++j) {
                            const u64 v = __hip_atomic_load(p + j, __ATOMIC_RELAXED,
                                                            __HIP_MEMORY_SCOPE_AGENT);
                            q[c*4 + j] = v;
                            bad |= (((unsigned)(v >> 16) & 0xFFFFu) ^ tagv);
                            bad |= (((unsigned)(v >> 48))           ^ tagv);
                        }
                    }
                    if (++guard > (1 << 20)) dead = true;
                } while (!dead && __any(bad != 0));
            }
            #pragma unroll
            for (int c = 0; c < 4; ++c) {
                union { unsigned u[4]; half8 h; } hu;
                #pragma unroll
                for (int j = 0; j < 4; ++j) {
                    const u64 v = q[c*4 + j];
                    hu.u[j] = ((unsigned)v & 0xFFFFu) | (((unsigned)(v >> 32)) << 16);
                }
                const half8 ah = hu.h;
                #pragma unroll
                for (int g = 0; g < 4; ++g) {
                    const half8 b = *(const half8*)(ldsw + ((((16 + kk0 + c)*4 + g) << 10) | (l << 4)));
                    acc[g] = __builtin_amdgcn_mfma_f32_16x16x32_f16(ah, b, acc[g], 0, 0, 0);
                }
            }
        }

        // ---- K-reduction across waves + epilogue (wave 0) ----
        __syncthreads();   // A: prev-step wave0 reduce-buffer reads are done
        if (w != 0) {
            #pragma unroll
            for (int g = 0; g < 4; ++g) *(f32x4*)&redb[w][g][l][0] = acc[g];
        }
        __syncthreads();   // B: partials visible
        if (w == 0) {
            #pragma unroll
            for (int g = 0; g < 4; ++g) {
                #pragma unroll
                for (int wv = 1; wv < 4; ++wv) acc[g] += *(f32x4*)&redb[wv][g][l][0];
            }
            f32x4 hv;
            #pragma unroll
            for (int r = 0; r < 4; ++r) {
                const float ig = 1.f / (1.f + __expf(-(acc[0][r] + bias0)));
                const float fg = 1.f / (1.f + __expf(-(acc[1][r] + bias1)));
                const float og = 1.f / (1.f + __expf(-(acc[2][r] + bias2)));
                const float gv = acc[3][r] + bias3;
                const float gg = 1.f - 2.f / (__expf(2.f*gv) + 1.f);        // tanh
                cst[r] = fg*cst[r] + ig*gg;
                hv[r]  = og * (1.f - 2.f / (__expf(2.f*cst[r]) + 1.f));
            }
            const int colg = s*16 + (l & 15);
            unsigned* hw = grpbuf + (size_t)((t + 1) & 1)*16*512;
            const unsigned tagw = (unsigned)(t + 1) << 16;
            // publish tagged h words: fire-and-forget relaxed agent atomics (no ack needed)
            #pragma unroll
            for (int r = 0; r < 4; ++r) {
                const int brow = (l >> 4)*4 + r;
                const unsigned short hb = __builtin_bit_cast(unsigned short, (_Float16)hv[r]);
                __hip_atomic_store(hw + brow*512 + colg, tagw | (unsigned)hb,
                                   __ATOMIC_RELAXED, __HIP_MEMORY_SCOPE_AGENT);
            }
            // out stores (normal cached f32)
            #pragma unroll
            for (int r = 0; r < 4; ++r) {
                const int brow = (l >> 4)*4 + r;
                out[((size_t)(bg*16 + brow)*NS + u)*1024 + (d << 9) + colg] = hv[r];
            }
        }
        #pragma unroll
        for (int g = 0; g < 4; ++g) acc[g] = zero4();
    }
}

// ---------------- launch ----------------

extern "C" void kernel_launch(void* const* d_in, const int* in_sizes, int n_in,
                              void* d_out, int out_size, void* d_ws, size_t ws_size,
                              hipStream_t stream) {
    const float* x = (const float*)d_in[0];
    char* ws = (char*)d_ws;
    _Float16* xb    = (_Float16*)ws;                                   // 16 MiB
    _Float16* WP    = (_Float16*)(ws + (16u << 20));                   // 8 MiB
    float*    biasP = (float*)(ws + (24u << 20));                      // 16 KiB
    unsigned* htag  = (unsigned*)(ws + (24u << 20) + (64u << 10));     // 512 KiB

    // clean tags every call (also across graph replays) -> sync is real each run
    hipMemsetAsync(htag, 0, 8u * 2u * 16u * 512u * 4u, stream);
    conv_x<<<4096, 256, 0, stream>>>(x, xb);
    // gate order g: 0=i(Wi) 1=f(Wf) 2=o(Wo) 3=g(Wc)
    pack_w<<<2048, 256, 0, stream>>>(
        (const float*)d_in[1],  (const float*)d_in[3],  (const float*)d_in[7],  (const float*)d_in[5],
        (const float*)d_in[9],  (const float*)d_in[11], (const float*)d_in[15], (const float*)d_in[13], WP);
    pack_bias<<<16, 256, 0, stream>>>(
        (const float*)d_in[2],  (const float*)d_in[4],  (const float*)d_in[8],  (const float*)d_in[6],
        (const float*)d_in[10], (const float*)d_in[12], (const float*)d_in[16], (const float*)d_in[14], biasP);
    lstm_scan<<<256, 256, 0, stream>>>(xb, WP, biasP, htag, (float*)d_out);
}

// Round 6
// 1135.300 us; speedup vs baseline: 2.0056x; 2.0056x over previous
//
#include <hip/hip_runtime.h>

// Bidirectional LSTM, B=64 S=256 I=H=512, f32 in/out.
// Persistent dataflow kernel: 256 WGs = 8 groups (2 dir x 4 batch-group) x 32 col-slices.
// Weights (fp16, MFMA-frag-packed) LDS-resident.
// Cross-WG h exchange (round 6):
//   data  : TAGGED words (tag<<16 | h_fp16) via relaxed agent-scope (IF$) atomics,
//           fire-and-forget (no store-ack on critical path); consumer verifies tags.
//   gate  : advisory per-producer flag, PADDED to 128B/flag (own IF$ line), polled by
//           ONE lane per consumer WG per flag with s_sleep backoff -> ~100x less line
//           contention than round 3 (which had 4096 pollers per 128B line).
// Mod-2 h buffering race-free by data-dependency backpressure (see r5 analysis).

typedef float    f32x4 __attribute__((ext_vector_type(4)));
typedef _Float16 half8 __attribute__((ext_vector_type(8)));
typedef unsigned long long u64;

#define NB 64
#define NS 256
#define NI 512
#define NH 512

__device__ inline f32x4 zero4() { f32x4 v; v[0]=0.f; v[1]=0.f; v[2]=0.f; v[3]=0.f; return v; }

// ---------------- prep kernels ----------------

__global__ void conv_x(const float* __restrict__ x, _Float16* __restrict__ xb) {
    const int i = blockIdx.x * 256 + threadIdx.x;
    const float4 a = ((const float4*)x)[2*i];
    const float4 b = ((const float4*)x)[2*i+1];
    half8 o;
    o[0]=(_Float16)a.x; o[1]=(_Float16)a.y; o[2]=(_Float16)a.z; o[3]=(_Float16)a.w;
    o[4]=(_Float16)b.x; o[5]=(_Float16)b.y; o[6]=(_Float16)b.z; o[7]=(_Float16)b.w;
    ((half8*)xb)[i] = o;
}

// WP[d][s][p][kk][g][l][j] = W_{d,g}[p*512 + kk*32 + (l>>4)*8 + j][s*16 + (l&15)]
__global__ void pack_w(const float* __restrict__ Wi_f, const float* __restrict__ Wf_f,
                       const float* __restrict__ Wo_f, const float* __restrict__ Wc_f,
                       const float* __restrict__ Wi_b, const float* __restrict__ Wf_b,
                       const float* __restrict__ Wo_b, const float* __restrict__ Wc_b,
                       _Float16* __restrict__ WP) {
    const int idx = blockIdx.x * 256 + threadIdx.x;
    const int l  = idx & 63;
    const int g  = (idx >> 6) & 3;
    const int kk = (idx >> 8) & 15;
    const int p  = (idx >> 12) & 1;
    const int s  = (idx >> 13) & 31;
    const int d  = (idx >> 18) & 1;
    const float* W;
    if (d == 0) W = (g==0) ? Wi_f : (g==1) ? Wf_f : (g==2) ? Wo_f : Wc_f;
    else        W = (g==0) ? Wi_b : (g==1) ? Wf_b : (g==2) ? Wo_b : Wc_b;
    const int r0 = p*512 + kk*32 + (l >> 4)*8;
    const int c  = s*16 + (l & 15);
    half8 v;
    #pragma unroll
    for (int j = 0; j < 8; ++j) v[j] = (_Float16)W[(size_t)(r0 + j)*NH + c];
    *(half8*)(WP + (size_t)idx*8) = v;
}

__global__ void pack_bias(const float* __restrict__ bi_f, const float* __restrict__ bf_f,
                          const float* __restrict__ bo_f, const float* __restrict__ bc_f,
                          const float* __restrict__ bi_b, const float* __restrict__ bf_b,
                          const float* __restrict__ bo_b, const float* __restrict__ bc_b,
                          float* __restrict__ biasP) {
    const int i = blockIdx.x * 256 + threadIdx.x;
    const int c = i & 511, g = (i >> 9) & 3, d = (i >> 11) & 1;
    const float* b;
    if (d == 0) b = (g==0) ? bi_f : (g==1) ? bf_f : (g==2) ? bo_f : bc_f;
    else        b = (g==0) ? bi_b : (g==1) ? bf_b : (g==2) ? bo_b : bc_b;
    biasP[i] = b[c];
}

// ---------------- main persistent scan kernel ----------------
// grid 256 x 256. LDS: 128KiB packed weights + 16KiB reduce buffer -> 1 WG/CU.

__global__ __launch_bounds__(256) void lstm_scan(
    const _Float16* __restrict__ xb,     // [64][256][512]
    const _Float16* __restrict__ WP,     // [2][32][2][16][4][64][8]
    const float*    __restrict__ biasP,  // [2][4][512]
    unsigned*       __restrict__ htag,   // [8 grp][2 buf][16 row][512 col] tagged h words
    unsigned*       __restrict__ flags,  // [8 grp][32 slice] padded: 32 dwords (128B) each
    float*          __restrict__ out)    // [64][256][1024]
{
    __shared__ char  ldsw[131072];
    __shared__ float redb[4][4][64][4];

    const int wg  = blockIdx.x;
    const int g8  = wg & 7;           // group = (d,bg); &7 keeps group-mates XCD-adjacent (perf only)
    const int s   = wg >> 3;          // column slice (16 h-cols)
    const int d   = g8 >> 2;          // direction
    const int bg  = g8 & 3;           // batch group (16 rows)
    const int tid = threadIdx.x;
    const int w   = tid >> 6;         // wave 0..3 (K-split)
    const int l   = tid & 63;

    // stage packed weight slice (128 KiB) into LDS
    {
        const uint4* src = (const uint4*)(WP + (size_t)(d*32 + s)*65536);
        uint4* dst = (uint4*)ldsw;
        #pragma unroll
        for (int i = 0; i < 32; ++i) dst[tid + i*256] = src[tid + i*256];
    }
    __syncthreads();

    float bias0 = 0.f, bias1 = 0.f, bias2 = 0.f, bias3 = 0.f;
    if (w == 0) {
        const int c = s*16 + (l & 15);
        bias0 = biasP[(d*4 + 0)*512 + c];
        bias1 = biasP[(d*4 + 1)*512 + c];
        bias2 = biasP[(d*4 + 2)*512 + c];
        bias3 = biasP[(d*4 + 3)*512 + c];
    }

    f32x4 acc[4];
    #pragma unroll
    for (int g = 0; g < 4; ++g) acc[g] = zero4();
    f32x4 cst = zero4();                  // cell state (wave 0 only)

    bool dead = false;                    // sticky guard-trip (anti-hang)

    const int arow = bg*16 + (l & 15);    // A-frag row = batch row
    const int kof  = (l >> 4) * 8;        // A/B frag k sub-offset
    const int kk0  = w * 4;               // this wave's first k-chunk

    unsigned* grpbuf = htag + (size_t)g8 * 2 * 16 * 512;
    // this wave's 8 producer flags; only lanes 0..7 poll (1 poller/WG/flag)
    unsigned* pollp  = flags + (size_t)(g8*32 + w*8 + (l & 7)) * 32;
    unsigned* myflag = flags + (size_t)(g8*32 + s) * 32;

    for (int t = 0; t < NS; ++t) {
        const int u = d ? (NS - 1 - t) : t;   // time index in x/out

        // ---- x A-frag loads + x-part MFMAs (independent of h) ----
        const _Float16* xp = xb + ((size_t)arow*NS + u)*NI + kof;
        half8 af[4];
        #pragma unroll
        for (int c = 0; c < 4; ++c) af[c] = *(const half8*)(xp + (kk0 + c)*32);
        #pragma unroll
        for (int c = 0; c < 4; ++c) {
            #pragma unroll
            for (int g = 0; g < 4; ++g) {
                const half8 b = *(const half8*)(ldsw + ((((kk0 + c)*4 + g) << 10) | (l << 4)));
                acc[g] = __builtin_amdgcn_mfma_f32_16x16x32_f16(af[c], b, acc[g], 0, 0, 0);
            }
        }

        // ---- h-part: advisory flag gate, then tag-verified h loads, then MFMAs ----
        if (t > 0) {
            const unsigned tagv = (unsigned)t;   // producer wrote tag = t for h_{t-1}

            // (1) low-traffic gate: 1 poller lane per flag, padded lines, sleep backoff
            if (!dead) {
                unsigned v = tagv;
                int guard = 0;
                for (;;) {
                    if (l < 8) v = __hip_atomic_load(pollp, __ATOMIC_RELAXED,
                                                     __HIP_MEMORY_SCOPE_AGENT);
                    if (!__any((int)(v < tagv))) break;
                    if (++guard > (1 << 16)) { dead = true; break; }
                    __builtin_amdgcn_s_sleep(2);
                }
            }

            // (2) authoritative tag-verified data read (normally single pass)
            const unsigned* base = grpbuf + (size_t)(t & 1)*16*512 + (l & 15)*512 + kof;
            u64 q[16];
            {
                int guard = 0;
                for (;;) {
                    unsigned bad = 0;
                    #pragma unroll
                    for (int c = 0; c < 4; ++c) {
                        const u64* p = (const u64*)(base + (kk0 + c)*32);
                        #pragma unroll
                        for (int j = 0; j < 4; ++j) {
                            const u64 v = __hip_atomic_load(p + j, __ATOMIC_RELAXED,
                                                            __HIP_MEMORY_SCOPE_AGENT);
                            q[c*4 + j] = v;
                            bad |= (((unsigned)(v >> 16) & 0xFFFFu) ^ tagv);
                            bad |= (((unsigned)(v >> 48))           ^ tagv);
                        }
                    }
                    if (!__any((int)(bad != 0))) break;
                    if (dead || ++guard > (1 << 16)) { dead = true; break; }
                    __builtin_amdgcn_s_sleep(1);
                }
            }
            #pragma unroll
            for (int c = 0; c < 4; ++c) {
                union { unsigned u[4]; half8 h; } hu;
                #pragma unroll
                for (int j = 0; j < 4; ++j) {
                    const u64 v = q[c*4 + j];
                    hu.u[j] = ((unsigned)v & 0xFFFFu) | (((unsigned)(v >> 32)) << 16);
                }
                const half8 ah = hu.h;
                #pragma unroll
                for (int g = 0; g < 4; ++g) {
                    const half8 b = *(const half8*)(ldsw + ((((16 + kk0 + c)*4 + g) << 10) | (l << 4)));
                    acc[g] = __builtin_amdgcn_mfma_f32_16x16x32_f16(ah, b, acc[g], 0, 0, 0);
                }
            }
        }

        // ---- K-reduction across waves + epilogue (wave 0) ----
        __syncthreads();   // A: prev-step wave0 reduce-buffer reads are done
        if (w != 0) {
            #pragma unroll
            for (int g = 0; g < 4; ++g) *(f32x4*)&redb[w][g][l][0] = acc[g];
        }
        __syncthreads();   // B: partials visible
        if (w == 0) {
            #pragma unroll
            for (int g = 0; g < 4; ++g) {
                #pragma unroll
                for (int wv = 1; wv < 4; ++wv) acc[g] += *(f32x4*)&redb[wv][g][l][0];
            }
            f32x4 hv;
            #pragma unroll
            for (int r = 0; r < 4; ++r) {
                const float ig = 1.f / (1.f + __expf(-(acc[0][r] + bias0)));
                const float fg = 1.f / (1.f + __expf(-(acc[1][r] + bias1)));
                const float og = 1.f / (1.f + __expf(-(acc[2][r] + bias2)));
                const float gv = acc[3][r] + bias3;
                const float gg = 1.f - 2.f / (__expf(2.f*gv) + 1.f);        // tanh
                cst[r] = fg*cst[r] + ig*gg;
                hv[r]  = og * (1.f - 2.f / (__expf(2.f*cst[r]) + 1.f));
            }
            const int colg = s*16 + (l & 15);
            unsigned* hw = grpbuf + (size_t)((t + 1) & 1)*16*512;
            const unsigned tagw = (unsigned)(t + 1) << 16;
            // publish tagged h words (fire-and-forget) ...
            #pragma unroll
            for (int r = 0; r < 4; ++r) {
                const int brow = (l >> 4)*4 + r;
                const unsigned short hb = __builtin_bit_cast(unsigned short, (_Float16)hv[r]);
                __hip_atomic_store(hw + brow*512 + colg, tagw | (unsigned)hb,
                                   __ATOMIC_RELAXED, __HIP_MEMORY_SCOPE_AGENT);
            }
            // ... then the advisory flag, immediately (no store-ack wait; tags are authoritative)
            if (l == 0)
                __hip_atomic_store(myflag, (unsigned)(t + 1),
                                   __ATOMIC_RELAXED, __HIP_MEMORY_SCOPE_AGENT);
            // out stores (normal cached f32), off the critical path
            #pragma unroll
            for (int r = 0; r < 4; ++r) {
                const int brow = (l >> 4)*4 + r;
                out[((size_t)(bg*16 + brow)*NS + u)*1024 + (d << 9) + colg] = hv[r];
            }
        }
        #pragma unroll
        for (int g = 0; g < 4; ++g) acc[g] = zero4();
    }
}

// ---------------- launch ----------------

extern "C" void kernel_launch(void* const* d_in, const int* in_sizes, int n_in,
                              void* d_out, int out_size, void* d_ws, size_t ws_size,
                              hipStream_t stream) {
    const float* x = (const float*)d_in[0];
    char* ws = (char*)d_ws;
    _Float16* xb    = (_Float16*)ws;                                   // 16 MiB
    _Float16* WP    = (_Float16*)(ws + (16u << 20));                   // 8 MiB
    float*    biasP = (float*)(ws + (24u << 20));                      // 16 KiB
    unsigned* htag  = (unsigned*)(ws + (24u << 20) + (64u << 10));     // 512 KiB tagged h
    unsigned* flags = (unsigned*)(ws + (24u << 20) + (64u << 10) + (512u << 10)); // 32 KiB padded flags

    // zero tags + flags every call (graph-replay deterministic): 512KiB + 32KiB contiguous
    hipMemsetAsync(htag, 0, (512u << 10) + (32u << 10), stream);
    conv_x<<<4096, 256, 0, stream>>>(x, xb);
    // gate order g: 0=i(Wi) 1=f(Wf) 2=o(Wo) 3=g(Wc)
    pack_w<<<2048, 256, 0, stream>>>(
        (const float*)d_in[1],  (const float*)d_in[3],  (const float*)d_in[7],  (const float*)d_in[5],
        (const float*)d_in[9],  (const float*)d_in[11], (const float*)d_in[15], (const float*)d_in[13], WP);
    pack_bias<<<16, 256, 0, stream>>>(
        (const float*)d_in[2],  (const float*)d_in[4],  (const float*)d_in[8],  (const float*)d_in[6],
        (const float*)d_in[10], (const float*)d_in[12], (const float*)d_in[16], (const float*)d_in[14], biasP);
    lstm_scan<<<256, 256, 0, stream>>>(xb, WP, biasP, htag, flags, (float*)d_out);
}

// Round 7
// 798.703 us; speedup vs baseline: 2.8509x; 1.4214x over previous
//
#include <hip/hip_runtime.h>

// Bidirectional LSTM, B=64 S=256 I=H=512, f32 in/out.
// Persistent dataflow kernel: 256 WGs = 8 groups (2 dir x 4 batch-group) x 32 col-slices.
// Weights (fp16, MFMA-frag-packed) LDS-resident.
// Round 7: (1) h exchanged in MFMA-A-FRAGMENT order (lane-contiguous 16B pulls, ~4x fewer
// IF$ line requests), tagged per u32 word (tag<<16 | h_fp16), relaxed agent-scope atomics,
// fire-and-forget publish; (2) distributed epilogue (all 4 waves: LDS partial exchange,
// each wave owns rows r==w); (3) per-wave flag-counter gating (cnt >= 4t), hot poll,
// no inter-wave barrier on the sync path. Tags remain the authoritative correctness check.

typedef float    f32x4 __attribute__((ext_vector_type(4)));
typedef _Float16 half8 __attribute__((ext_vector_type(8)));
typedef unsigned long long u64;

#define NB 64
#define NS 256
#define NI 512
#define NH 512

__device__ inline f32x4 zero4() { f32x4 v; v[0]=0.f; v[1]=0.f; v[2]=0.f; v[3]=0.f; return v; }

// ---------------- prep kernels ----------------

__global__ void conv_x(const float* __restrict__ x, _Float16* __restrict__ xb) {
    const int i = blockIdx.x * 256 + threadIdx.x;
    const float4 a = ((const float4*)x)[2*i];
    const float4 b = ((const float4*)x)[2*i+1];
    half8 o;
    o[0]=(_Float16)a.x; o[1]=(_Float16)a.y; o[2]=(_Float16)a.z; o[3]=(_Float16)a.w;
    o[4]=(_Float16)b.x; o[5]=(_Float16)b.y; o[6]=(_Float16)b.z; o[7]=(_Float16)b.w;
    ((half8*)xb)[i] = o;
}

// WP[d][s][p][kk][g][l][j] = W_{d,g}[p*512 + kk*32 + (l>>4)*8 + j][s*16 + (l&15)]
__global__ void pack_w(const float* __restrict__ Wi_f, const float* __restrict__ Wf_f,
                       const float* __restrict__ Wo_f, const float* __restrict__ Wc_f,
                       const float* __restrict__ Wi_b, const float* __restrict__ Wf_b,
                       const float* __restrict__ Wo_b, const float* __restrict__ Wc_b,
                       _Float16* __restrict__ WP) {
    const int idx = blockIdx.x * 256 + threadIdx.x;
    const int l  = idx & 63;
    const int g  = (idx >> 6) & 3;
    const int kk = (idx >> 8) & 15;
    const int p  = (idx >> 12) & 1;
    const int s  = (idx >> 13) & 31;
    const int d  = (idx >> 18) & 1;
    const float* W;
    if (d == 0) W = (g==0) ? Wi_f : (g==1) ? Wf_f : (g==2) ? Wo_f : Wc_f;
    else        W = (g==0) ? Wi_b : (g==1) ? Wf_b : (g==2) ? Wo_b : Wc_b;
    const int r0 = p*512 + kk*32 + (l >> 4)*8;
    const int c  = s*16 + (l & 15);
    half8 v;
    #pragma unroll
    for (int j = 0; j < 8; ++j) v[j] = (_Float16)W[(size_t)(r0 + j)*NH + c];
    *(half8*)(WP + (size_t)idx*8) = v;
}

__global__ void pack_bias(const float* __restrict__ bi_f, const float* __restrict__ bf_f,
                          const float* __restrict__ bo_f, const float* __restrict__ bc_f,
                          const float* __restrict__ bi_b, const float* __restrict__ bf_b,
                          const float* __restrict__ bo_b, const float* __restrict__ bc_b,
                          float* __restrict__ biasP) {
    const int i = blockIdx.x * 256 + threadIdx.x;
    const int c = i & 511, g = (i >> 9) & 3, d = (i >> 11) & 1;
    const float* b;
    if (d == 0) b = (g==0) ? bi_f : (g==1) ? bf_f : (g==2) ? bo_f : bc_f;
    else        b = (g==0) ? bi_b : (g==1) ? bf_b : (g==2) ? bo_b : bc_b;
    biasP[i] = b[c];
}

// ---------------- main persistent scan kernel ----------------
// grid 256 x 256. LDS: 128KiB packed weights + 16KiB partial-sum buffer -> 1 WG/CU.
//
// hfrag layout (per group, per buf): [kk(16)][p(2)][lane64(64)][slot(4)] u32 tagged words.
//   word for h[row][c] (c = h-col 0..511): kk=c>>5, p=(c>>2)&1, lane64=((c>>3)&3)*16+row,
//   slot=c&3, value = (tag<<16) | fp16(h).
// Consumer wave w, lane l, chunk c: ah elem j = word at [kk=w*4+c][p=j>>2][l][j&3]
//   -> two 16B-contiguous pulls per (kk,p), lane-stride 16B.

__global__ __launch_bounds__(256) void lstm_scan(
    const _Float16* __restrict__ xb,     // [64][256][512]
    const _Float16* __restrict__ WP,     // [2][32][2][16][4][64][8]
    const float*    __restrict__ biasP,  // [2][4][512]
    unsigned*       __restrict__ hfrag,  // [8 grp][2 buf][8192 u32]
    unsigned*       __restrict__ flags,  // [8 grp][32 slice] padded 32 dwords (128B) each
    float*          __restrict__ out)    // [64][256][1024]
{
    __shared__ char  ldsw[131072];
    __shared__ float redb[4][4][4][64];  // [wv][gate][r][lane]

    const int wg  = blockIdx.x;
    const int g8  = wg & 7;           // group = (d,bg); &7 keeps group-mates XCD-adjacent (perf only)
    const int s   = wg >> 3;          // column slice (16 h-cols)
    const int d   = g8 >> 2;          // direction
    const int bg  = g8 & 3;           // batch group (16 rows)
    const int tid = threadIdx.x;
    const int w   = tid >> 6;         // wave 0..3 (K-split; owns rows r==w in epilogue)
    const int l   = tid & 63;

    // stage packed weight slice (128 KiB) into LDS
    {
        const uint4* src = (const uint4*)(WP + (size_t)(d*32 + s)*65536);
        uint4* dst = (uint4*)ldsw;
        #pragma unroll
        for (int i = 0; i < 32; ++i) dst[tid + i*256] = src[tid + i*256];
    }
    __syncthreads();

    // ---- per-thread epilogue ownership: (row_local, col_local) ----
    const int row_local = (l >> 4)*4 + w;     // 0..15
    const int col_local = l & 15;
    const int colg      = s*16 + col_local;   // h column 0..511
    const float bias0 = biasP[(d*4 + 0)*512 + colg];
    const float bias1 = biasP[(d*4 + 1)*512 + colg];
    const float bias2 = biasP[(d*4 + 2)*512 + colg];
    const float bias3 = biasP[(d*4 + 3)*512 + colg];
    float cstv = 0.f;                          // cell state (1 per thread)

    // publish offset for this thread's h word (within one buf, u32 units)
    const int myoff = (colg >> 5)*512 + ((colg >> 2) & 1)*256
                    + (((colg >> 3) & 3)*16 + row_local)*4 + (colg & 3);
    unsigned* grpfrag = hfrag + (size_t)g8 * 16384;   // 2 bufs x 8192
    unsigned* myflag  = flags + (size_t)(g8*32 + s) * 32;
    unsigned* pollp   = flags + (size_t)(g8*32 + w*8 + (l & 7)) * 32;

    f32x4 acc[4];
    #pragma unroll
    for (int g = 0; g < 4; ++g) acc[g] = zero4();

    bool dead = false;                    // sticky guard-trip (anti-hang)

    const int arow = bg*16 + (l & 15);    // x A-frag row = batch row
    const int kof  = (l >> 4) * 8;        // A/B frag k sub-offset
    const int kk0  = w * 4;               // this wave's first k-chunk

    for (int t = 0; t < NS; ++t) {
        const int u = d ? (NS - 1 - t) : t;   // time index in x/out

        // ---- x A-frag loads + x-part MFMAs (independent of h) ----
        const _Float16* xp = xb + ((size_t)arow*NS + u)*NI + kof;
        half8 af[4];
        #pragma unroll
        for (int c = 0; c < 4; ++c) af[c] = *(const half8*)(xp + (kk0 + c)*32);
        #pragma unroll
        for (int c = 0; c < 4; ++c) {
            #pragma unroll
            for (int g = 0; g < 4; ++g) {
                const half8 b = *(const half8*)(ldsw + ((((kk0 + c)*4 + g) << 10) | (l << 4)));
                acc[g] = __builtin_amdgcn_mfma_f32_16x16x32_f16(af[c], b, acc[g], 0, 0, 0);
            }
        }

        // ---- h-part: per-wave counter gate (hot poll), frag-order pull, tag verify, MFMAs ----
        if (t > 0) {
            const unsigned tagv = (unsigned)t;
            const unsigned tgt4 = 4u * (unsigned)t;

            // gate: this wave's lanes 0..7 poll its 8 producer counters
            if (!dead) {
                unsigned v = 0xFFFFFFFFu;
                int guard = 0;
                for (;;) {
                    if (l < 8) v = __hip_atomic_load(pollp, __ATOMIC_RELAXED,
                                                     __HIP_MEMORY_SCOPE_AGENT);
                    if (!__any(v < tgt4)) break;
                    if (++guard > (1 << 18)) { dead = true; break; }
                }
            }

            // pull: 16 u64 loads, lane-contiguous 16B blocks; verify tags (authoritative)
            const unsigned* gb = grpfrag + (size_t)(t & 1)*8192;
            u64 q[16];
            {
                int guard = 0;
                for (;;) {
                    unsigned bad = 0;
                    #pragma unroll
                    for (int c = 0; c < 4; ++c) {
                        const unsigned* blk = gb + (kk0 + c)*512;
                        const u64* p0 = (const u64*)(blk + l*4);
                        const u64* p1 = (const u64*)(blk + 256 + l*4);
                        q[c*4+0] = __hip_atomic_load(p0,     __ATOMIC_RELAXED, __HIP_MEMORY_SCOPE_AGENT);
                        q[c*4+1] = __hip_atomic_load(p0 + 1, __ATOMIC_RELAXED, __HIP_MEMORY_SCOPE_AGENT);
                        q[c*4+2] = __hip_atomic_load(p1,     __ATOMIC_RELAXED, __HIP_MEMORY_SCOPE_AGENT);
                        q[c*4+3] = __hip_atomic_load(p1 + 1, __ATOMIC_RELAXED, __HIP_MEMORY_SCOPE_AGENT);
                        #pragma unroll
                        for (int j = 0; j < 4; ++j) {
                            const u64 v = q[c*4 + j];
                            bad |= (((unsigned)(v >> 16) & 0xFFFFu) ^ tagv);
                            bad |= (((unsigned)(v >> 48))           ^ tagv);
                        }
                    }
                    if (!__any(bad != 0)) break;
                    if (dead || ++guard > (1 << 16)) { dead = true; break; }
                    __builtin_amdgcn_s_sleep(1);
                }
            }
            #pragma unroll
            for (int c = 0; c < 4; ++c) {
                union { unsigned uu[4]; half8 h; } hu;
                #pragma unroll
                for (int j = 0; j < 4; ++j) {
                    const u64 v = q[c*4 + j];
                    hu.uu[j] = ((unsigned)v & 0xFFFFu) | (((unsigned)(v >> 32)) << 16);
                }
                const half8 ah = hu.h;
                #pragma unroll
                for (int g = 0; g < 4; ++g) {
                    const half8 b = *(const half8*)(ldsw + ((((16 + kk0 + c)*4 + g) << 10) | (l << 4)));
                    acc[g] = __builtin_amdgcn_mfma_f32_16x16x32_f16(ah, b, acc[g], 0, 0, 0);
                }
            }
        }

        // ---- cross-wave partial exchange + distributed epilogue ----
        __syncthreads();   // BARRIER1: prev-step epilogue reads of redb are done
        #pragma unroll
        for (int g = 0; g < 4; ++g) {
            #pragma unroll
            for (int r = 0; r < 4; ++r) redb[w][g][r][l] = acc[g][r];
        }
        __syncthreads();   // BARRIER2: all partials visible
        {
            float s0 = 0.f, s1 = 0.f, s2 = 0.f, s3 = 0.f;
            #pragma unroll
            for (int wv = 0; wv < 4; ++wv) {
                s0 += redb[wv][0][w][l];
                s1 += redb[wv][1][w][l];
                s2 += redb[wv][2][w][l];
                s3 += redb[wv][3][w][l];
            }
            const float ig = 1.f / (1.f + __expf(-(s0 + bias0)));
            const float fg = 1.f / (1.f + __expf(-(s1 + bias1)));
            const float og = 1.f / (1.f + __expf(-(s2 + bias2)));
            const float gv = s3 + bias3;
            const float gg = 1.f - 2.f / (__expf(2.f*gv) + 1.f);        // tanh
            cstv = fg*cstv + ig*gg;
            const float hvv = og * (1.f - 2.f / (__expf(2.f*cstv) + 1.f));

            // publish tagged h word (fire-and-forget), then bump this wave's counter
            const unsigned short hb = __builtin_bit_cast(unsigned short, (_Float16)hvv);
            const unsigned word = ((unsigned)(t + 1) << 16) | (unsigned)hb;
            __hip_atomic_store(grpfrag + (size_t)((t + 1) & 1)*8192 + myoff, word,
                               __ATOMIC_RELAXED, __HIP_MEMORY_SCOPE_AGENT);
            if (l == 0)
                (void)__hip_atomic_fetch_add(myflag, 1u, __ATOMIC_RELAXED,
                                             __HIP_MEMORY_SCOPE_AGENT);
            // out store (off critical path)
            out[((size_t)(bg*16 + row_local)*NS + u)*1024 + (d << 9) + colg] = hvv;
        }
        #pragma unroll
        for (int g = 0; g < 4; ++g) acc[g] = zero4();
    }
}

// ---------------- launch ----------------

extern "C" void kernel_launch(void* const* d_in, const int* in_sizes, int n_in,
                              void* d_out, int out_size, void* d_ws, size_t ws_size,
                              hipStream_t stream) {
    const float* x = (const float*)d_in[0];
    char* ws = (char*)d_ws;
    _Float16* xb    = (_Float16*)ws;                                   // 16 MiB
    _Float16* WP    = (_Float16*)(ws + (16u << 20));                   // 8 MiB
    float*    biasP = (float*)(ws + (24u << 20));                      // 16 KiB
    unsigned* hfrag = (unsigned*)(ws + (24u << 20) + (64u << 10));     // 512 KiB frag-order h
    unsigned* flags = (unsigned*)(ws + (24u << 20) + (64u << 10) + (512u << 10)); // 32 KiB counters

    // zero tags + counters every call (graph-replay deterministic)
    hipMemsetAsync(hfrag, 0, (512u << 10) + (32u << 10), stream);
    conv_x<<<4096, 256, 0, stream>>>(x, xb);
    // gate order g: 0=i(Wi) 1=f(Wf) 2=o(Wo) 3=g(Wc)
    pack_w<<<2048, 256, 0, stream>>>(
        (const float*)d_in[1],  (const float*)d_in[3],  (const float*)d_in[7],  (const float*)d_in[5],
        (const float*)d_in[9],  (const float*)d_in[11], (const float*)d_in[15], (const float*)d_in[13], WP);
    pack_bias<<<16, 256, 0, stream>>>(
        (const float*)d_in[2],  (const float*)d_in[4],  (const float*)d_in[8],  (const float*)d_in[6],
        (const float*)d_in[10], (const float*)d_in[12], (const float*)d_in[16], (const float*)d_in[14], biasP);
    lstm_scan<<<256, 256, 0, stream>>>(xb, WP, biasP, hfrag, flags, (float*)d_out);
}